// Round 2
// baseline (335.062 us; speedup 1.0000x reference)
//
#include <hip/hip_runtime.h>
#include <hip/hip_bf16.h>

#define N_NODES 4096
#define DIMC    256   // H*D, also K of both layer GEMMs
#define NHEADS  4
#define LOG2E   1.44269504f

typedef __attribute__((ext_vector_type(8))) short  short8;
typedef __attribute__((ext_vector_type(4))) short  short4v;
typedef __attribute__((ext_vector_type(4))) float  float4v;

union S8U { short8 v; unsigned int u[4]; };

#if __has_builtin(__builtin_amdgcn_exp2f)
#define EXP2(x) __builtin_amdgcn_exp2f(x)
#else
#define EXP2(x) exp2f(x)
#endif

__device__ inline unsigned short bf16_bits(__hip_bfloat16 b) {
  union { __hip_bfloat16 b; unsigned short u; } cv; cv.b = b; return cv.u;
}

// monotone float<->u32 encode for atomicMax over signed floats
__device__ inline unsigned fenc(float f) {
  unsigned u = __float_as_uint(f);
  return (u & 0x80000000u) ? ~u : (u | 0x80000000u);
}
__device__ inline float fdec(unsigned k) {
  unsigned u = (k & 0x80000000u) ? (k & 0x7FFFFFFFu) : ~k;
  return __uint_as_float(u);
}

// ---------------- adjacency -> bitmask (1 bit per edge) ----------------
__global__ __launch_bounds__(256) void pack_adj_kernel(
    const int* __restrict__ adj, unsigned long long* __restrict__ bits)
{
  int wid  = blockIdx.x * 4 + (threadIdx.x >> 6);
  int lane = threadIdx.x & 63;
  int row  = wid >> 6;
  int w64  = wid & 63;
  int v = adj[(size_t)row * N_NODES + w64 * 64 + lane];
  unsigned long long m = __ballot(v > 0);
  if (lane == 0) bits[row * 64 + w64] = m;
}

// ------------- fp32 -> split bf16 (hi + residual lo), elementwise --------
__global__ __launch_bounds__(256) void split_kernel(
    const float* __restrict__ in, __hip_bfloat16* __restrict__ hi,
    __hip_bfloat16* __restrict__ lo, int n)
{
  int i = blockIdx.x * 256 + threadIdx.x;
  if (i < n) {
    float v = in[i];
    __hip_bfloat16 h = __float2bfloat16(v);
    hi[i] = h;
    lo[i] = __float2bfloat16(v - __bfloat162float(h));
  }
}

// ------- fp32 transpose + split: in[B][R][C] -> outhi(/lo)[B][C][R] ------
// (weights only now). grid (R/32, C/32, B), block 256.
__global__ __launch_bounds__(256) void transpose_split_kernel(
    const float* __restrict__ in, __hip_bfloat16* __restrict__ outhi,
    __hip_bfloat16* __restrict__ outlo, int R, int C)
{
  __shared__ float tile[32][33];
  int t = threadIdx.x;
  int r0 = blockIdx.x * 32, c0 = blockIdx.y * 32;
  size_t base = (size_t)blockIdx.z * R * C;
  int tr = t >> 3, tc = (t & 7) * 4;
  const float* ip = in + base;
  float4v v = *reinterpret_cast<const float4v*>(ip + (size_t)(r0 + tr) * C + c0 + tc);
#pragma unroll
  for (int k = 0; k < 4; ++k) tile[tr][tc + k] = v[k];
  __syncthreads();
  short4v oh, ol;
#pragma unroll
  for (int k = 0; k < 4; ++k) {
    float f = tile[tc + k][tr];
    __hip_bfloat16 hb = __float2bfloat16(f);
    __hip_bfloat16 lb = __float2bfloat16(f - __bfloat162float(hb));
    oh[k] = (short)bf16_bits(hb);
    ol[k] = (short)bf16_bits(lb);
  }
  size_t oidx = base + (size_t)(c0 + tr) * R + r0 + tc;
  *reinterpret_cast<short4v*>(reinterpret_cast<unsigned short*>(outhi) + oidx) = oh;
  if (outlo)
    *reinterpret_cast<short4v*>(reinterpret_cast<unsigned short*>(outlo) + oidx) = ol;
}

// ------------- h GEMM (split-bf16) + fused transpose epilogue ------------
// out[n][c] fp32 row-major AND hTh[c][n] bf16 (hi) in one kernel.
// grid (128,8), block 256 (4 waves, 16x16 sub-tiles).
__global__ __launch_bounds__(256) void gemm_kernel(
    const __hip_bfloat16* __restrict__ Xhi, const __hip_bfloat16* __restrict__ Xlo,
    const __hip_bfloat16* __restrict__ WThi, const __hip_bfloat16* __restrict__ WTlo,
    float* __restrict__ out, __hip_bfloat16* __restrict__ hTh)
{
  __shared__ float tl[32][33];
  int t = threadIdx.x;
  int wv = t >> 6, lane = t & 63, quad = lane >> 4, col = lane & 15;
  int br = blockIdx.x * 32, bc = blockIdx.y * 32;
  int r0 = br + (wv >> 1) * 16;
  int c0 = bc + (wv & 1) * 16;
  float4v acc = {0, 0, 0, 0};
  const unsigned short* Xh = reinterpret_cast<const unsigned short*>(Xhi);
  const unsigned short* Xl = reinterpret_cast<const unsigned short*>(Xlo);
  const unsigned short* Wh = reinterpret_cast<const unsigned short*>(WThi);
  const unsigned short* Wl = reinterpret_cast<const unsigned short*>(WTlo);
#pragma unroll
  for (int k0 = 0; k0 < DIMC; k0 += 32) {
    size_t ao = (size_t)(r0 + col) * DIMC + k0 + quad * 8;
    size_t bo = (size_t)(c0 + col) * DIMC + k0 + quad * 8;
    short8 ah = *reinterpret_cast<const short8*>(Xh + ao);
    short8 al = *reinterpret_cast<const short8*>(Xl + ao);
    short8 bh = *reinterpret_cast<const short8*>(Wh + bo);
    short8 bl = *reinterpret_cast<const short8*>(Wl + bo);
    acc = __builtin_amdgcn_mfma_f32_16x16x32_bf16(ah, bh, acc, 0, 0, 0);
    acc = __builtin_amdgcn_mfma_f32_16x16x32_bf16(ah, bl, acc, 0, 0, 0);
    acc = __builtin_amdgcn_mfma_f32_16x16x32_bf16(al, bh, acc, 0, 0, 0);
  }
  int lr = (wv >> 1) * 16 + quad * 4, lc = (wv & 1) * 16 + col;
#pragma unroll
  for (int r = 0; r < 4; ++r) {
    out[(size_t)(r0 + quad * 4 + r) * DIMC + c0 + col] = acc[r];
    tl[lr + r][lc] = acc[r];
  }
  __syncthreads();
  int tr = t >> 3, tc = (t & 7) * 4;
  short4v oh;
#pragma unroll
  for (int k = 0; k < 4; ++k)
    oh[k] = (short)bf16_bits(__float2bfloat16(tl[tc + k][tr]));
  *reinterpret_cast<short4v*>(
      reinterpret_cast<unsigned short*>(hTh) + (size_t)(bc + tr) * N_NODES + br + tc) = oh;
}

// ---- f1/f2 (log2-scaled) + fused per-head global max (encoded atomic) ---
// grid 1024, block 256: wave per node.
__global__ __launch_bounds__(256) void fvec_kernel(
    const float* __restrict__ hA, const float* __restrict__ a,
    float* __restrict__ f1L, float* __restrict__ f2L,
    unsigned* __restrict__ f2enc)
{
  __shared__ float bm[4][4];  // [wave][head]
  int t = threadIdx.x, wv = t >> 6, lane = t & 63;
  int n = blockIdx.x * 4 + wv;
  int h = lane >> 4, d4 = (lane & 15) * 4;
  float4v v = *reinterpret_cast<const float4v*>(hA + (size_t)n * DIMC + lane * 4);
  const float* ah = a + h * 128;
  float s1 = v[0]*ah[d4] + v[1]*ah[d4+1] + v[2]*ah[d4+2] + v[3]*ah[d4+3];
  float s2 = v[0]*ah[64+d4] + v[1]*ah[64+d4+1] + v[2]*ah[64+d4+2] + v[3]*ah[64+d4+3];
#pragma unroll
  for (int o = 8; o >= 1; o >>= 1) {
    s1 += __shfl_xor(s1, o);
    s2 += __shfl_xor(s2, o);
  }
  float s2s = s2 * LOG2E;
  if ((lane & 15) == 0) {
    f1L[h * N_NODES + n] = s1 * LOG2E;
    f2L[h * N_NODES + n] = s2s;
    bm[wv][h] = s2s;
  }
  __syncthreads();
  if (t < 4) {
    float m = fmaxf(fmaxf(bm[0][t], bm[1][t]), fmaxf(bm[2][t], bm[3][t]));
    atomicMax(f2enc + t, fenc(m));
  }
}

// ------ fused masked-softmax attention, full-j, normalize + elu + out ----
// grid (64, 4) = (i-tile, head). block 512 = 8 waves: wr=wv>>1 row-group,
// wc=wv&1 D-half. Full 4096-j sweep -> denominator complete in-register:
// write FINAL output (split-bf16 for layer1, fp32 for layer2). No pbuf.
__global__ __launch_bounds__(512, 2) void attn_kernel(
    const __hip_bfloat16* __restrict__ hThi,   // [256][4096], row c = h*64+d
    const float* __restrict__ f1L, const float* __restrict__ f2L,
    const unsigned* __restrict__ f2enc,
    const unsigned long long* __restrict__ bits64, // [4096][64]
    float* __restrict__ outf, __hip_bfloat16* __restrict__ outhi,
    __hip_bfloat16* __restrict__ outlo)
{
  __shared__ __align__(16) unsigned short hs[2][64 * 72]; // stride 72 u16 = 144B
  int t = threadIdx.x;
  int wv = t >> 6, lane = t & 63, quad = lane >> 4, col = lane & 15;
  int wr = wv >> 1, wc = wv & 1;
  int it = blockIdx.x, h = blockIdx.y;
  int i0 = it * 64;
  int irow = i0 + wr * 16 + col;

  float f2m = fdec(f2enc[h]);
  float f1i = f1L[h * N_NODES + irow];
  float s0 = f1i + f2m;
  float m = fmaxf(s0, 0.2f * s0);   // lrelu monotone -> valid upper-bound shift
  float f1m = f1i - m;              // s' = f1m + fv;  lr-m = max(s', 0.2*s'+cm)
  float cm = -0.8f * m;

  const unsigned short* H =
      reinterpret_cast<const unsigned short*>(hThi) + (size_t)h * 64 * N_NODES;
  const float* f2h = f2L + h * N_NODES;
  const unsigned long long* brow = bits64 + (size_t)irow * 64;

  int srow = t >> 3, soff = (t & 7) * 8;   // 512 thr: one short8 each, 64x64 tile
  const unsigned short* g0 = H + (size_t)srow * N_NODES + soff;
  int l0 = srow * 72 + soff;

  float4v acc[2] = {{0,0,0,0},{0,0,0,0}};
  float4v accl = {0, 0, 0, 0};
  S8U ones;
  ones.u[0] = ones.u[1] = ones.u[2] = ones.u[3] = 0x3F803F80u; // bf16 1.0 x2

  // preload tile 0 into buffer 0
  short8 rA = *reinterpret_cast<const short8*>(g0);
  *reinterpret_cast<short8*>(&hs[0][l0]) = rA;
  __syncthreads();

  const int T = N_NODES / 64;  // 64
  for (int ti = 0; ti < T; ++ti) {
    int p = ti & 1;
    int j0 = ti * 64;
    if (ti + 1 < T)                 // prefetch next tile (global -> regs)
      rA = *reinterpret_cast<const short8*>(g0 + j0 + 64);
    unsigned long long wq = brow[ti] >> (quad * 8);
    unsigned int wb0 = (unsigned int)wq;
    unsigned int wb1 = (unsigned int)(wq >> 32);
    const unsigned short* bufp = hs[p];
#pragma unroll
    for (int jh = 0; jh < 2; ++jh) {
      unsigned int wb = jh ? wb1 : wb0;
      const float* fp = f2h + j0 + jh * 32 + quad * 8;
      float4v fa = *reinterpret_cast<const float4v*>(fp);
      float4v fb = *reinterpret_cast<const float4v*>(fp + 4);
      float w[8];
#pragma unroll
      for (int jj = 0; jj < 8; ++jj) {
        float fv = (jj < 4) ? fa[jj] : fb[jj - 4];
        float sp = f1m + fv;
        float tb = __builtin_fmaf(0.2f, sp, cm);
        float lr = fmaxf(sp, tb);
        float e = EXP2(lr);
        w[jj] = (wb & (1u << jj)) ? e : 0.0f;
      }
      S8U afr;
#pragma unroll
      for (int k2 = 0; k2 < 4; ++k2)   // truncate-pack two fp32 -> bf16x2
        afr.u[k2] = __builtin_amdgcn_perm(__float_as_uint(w[2 * k2 + 1]),
                                          __float_as_uint(w[2 * k2]),
                                          0x07060302u);
#pragma unroll
      for (int db = 0; db < 2; ++db) {
        short8 bfr = *reinterpret_cast<const short8*>(
            bufp + (wc * 32 + db * 16 + col) * 72 + jh * 32 + quad * 8);
        acc[db] = __builtin_amdgcn_mfma_f32_16x16x32_bf16(afr.v, bfr, acc[db], 0, 0, 0);
      }
      accl = __builtin_amdgcn_mfma_f32_16x16x32_bf16(afr.v, ones.v, accl, 0, 0, 0);
    }
    if (ti + 1 < T)                 // stage next tile into other buffer
      *reinterpret_cast<short8*>(&hs[p ^ 1][l0]) = rA;
    __syncthreads();                // single barrier per iteration
  }

  // C/D layout: col=lane&15, row=quad*4+reg. accl[r] = row sum (any col).
#pragma unroll
  for (int r = 0; r < 4; ++r) {
    float rl = 1.0f / accl[r];
    int n = i0 + wr * 16 + quad * 4 + r;
#pragma unroll
    for (int db = 0; db < 2; ++db) {
      float v = acc[db][r] * rl;
      float o = v > 0.f ? v : EXP2(v * LOG2E) - 1.0f;
      size_t oo = (size_t)n * DIMC + h * 64 + wc * 32 + db * 16 + col;
      if (outf) {
        outf[oo] = o;
      } else {
        __hip_bfloat16 hb = __float2bfloat16(o);
        outhi[oo] = hb;
        outlo[oo] = __float2bfloat16(o - __bfloat162float(hb));
      }
    }
  }
}

extern "C" void kernel_launch(void* const* d_in, const int* in_sizes, int n_in,
                              void* d_out, int out_size, void* d_ws, size_t ws_size,
                              hipStream_t stream)
{
  // inputs: t, x, adj, W1, a1, W2, a2  (fp32 except adj int32)
  const float* x   = (const float*)d_in[1];
  const int*   adj = (const int*)d_in[2];
  const float* W1  = (const float*)d_in[3];
  const float* a1  = (const float*)d_in[4];
  const float* W2  = (const float*)d_in[5];
  const float* a2  = (const float*)d_in[6];

  char* ws = (char*)d_ws;
  size_t off = 0;
  auto alloc = [&](size_t b) { size_t o = off; off = (off + b + 255) & ~255ULL; return o; };
  size_t o_bits = alloc((size_t)N_NODES * 64 * 8);          // 2 MB bitmask
  size_t o_w1h  = alloc((size_t)DIMC * DIMC * 2);
  size_t o_w1l  = alloc((size_t)DIMC * DIMC * 2);
  size_t o_w2h  = alloc((size_t)DIMC * DIMC * 2);
  size_t o_w2l  = alloc((size_t)DIMC * DIMC * 2);
  size_t o_xh   = alloc((size_t)N_NODES * DIMC * 2);
  size_t o_xl   = alloc((size_t)N_NODES * DIMC * 2);
  size_t o_hA   = alloc((size_t)N_NODES * DIMC * 4);        // h fp32 row-major
  size_t o_hTh  = alloc((size_t)N_NODES * DIMC * 2);        // h^T hi only
  size_t o_x2h  = alloc((size_t)N_NODES * DIMC * 2);
  size_t o_x2l  = alloc((size_t)N_NODES * DIMC * 2);
  size_t o_f1   = alloc((size_t)NHEADS * N_NODES * 4);
  size_t o_f2   = alloc((size_t)NHEADS * N_NODES * 4);
  size_t o_fm   = alloc(256);                               // 2 layers x 4 u32 (encoded max)

  unsigned long long* bits = (unsigned long long*)(ws + o_bits);
  __hip_bfloat16* w1h = (__hip_bfloat16*)(ws + o_w1h);
  __hip_bfloat16* w1l = (__hip_bfloat16*)(ws + o_w1l);
  __hip_bfloat16* w2h = (__hip_bfloat16*)(ws + o_w2h);
  __hip_bfloat16* w2l = (__hip_bfloat16*)(ws + o_w2l);
  __hip_bfloat16* xh  = (__hip_bfloat16*)(ws + o_xh);
  __hip_bfloat16* xl  = (__hip_bfloat16*)(ws + o_xl);
  float*          hA  = (float*)(ws + o_hA);
  __hip_bfloat16* hTh = (__hip_bfloat16*)(ws + o_hTh);
  __hip_bfloat16* x2h = (__hip_bfloat16*)(ws + o_x2h);
  __hip_bfloat16* x2l = (__hip_bfloat16*)(ws + o_x2l);
  float* f1p = (float*)(ws + o_f1);
  float* f2p = (float*)(ws + o_f2);
  unsigned* fme = (unsigned*)(ws + o_fm);

  hipMemsetAsync(ws + o_fm, 0, 64, stream);  // encoded-max init (monotone min)
  pack_adj_kernel<<<N_NODES * 64 / 4, 256, 0, stream>>>(adj, bits);
  transpose_split_kernel<<<dim3(8, 2, 4), 256, 0, stream>>>(W1, w1h, w1l, 256, 64);
  transpose_split_kernel<<<dim3(8, 2, 4), 256, 0, stream>>>(W2, w2h, w2l, 256, 64);
  split_kernel<<<N_NODES * DIMC / 256, 256, 0, stream>>>(x, xh, xl, N_NODES * DIMC);

  auto layer = [&](const __hip_bfloat16* xih, const __hip_bfloat16* xil,
                   const __hip_bfloat16* wth, const __hip_bfloat16* wtl,
                   const float* av, unsigned* fmk, float* outf,
                   __hip_bfloat16* oh, __hip_bfloat16* ol) {
    gemm_kernel<<<dim3(128, 8), 256, 0, stream>>>(xih, xil, wth, wtl, hA, hTh);
    fvec_kernel<<<1024, 256, 0, stream>>>(hA, av, f1p, f2p, fmk);
    attn_kernel<<<dim3(64, 4), 512, 0, stream>>>(hTh, f1p, f2p, fmk, bits,
                                                 outf, oh, ol);
  };

  layer(xh,  xl,  w1h, w1l, a1, fme,     nullptr,        x2h, x2l);
  layer(x2h, x2l, w2h, w2l, a2, fme + 4, (float*)d_out,  nullptr, nullptr);
}